// Round 1
// baseline (453.013 us; speedup 1.0000x reference)
//
#include <hip/hip_runtime.h>

#define NTOK 16384
#define DIM  128
#define NJT  128   // number of 128-wide j tiles

typedef __attribute__((ext_vector_type(8))) short short8;
typedef __attribute__((ext_vector_type(4))) float f32x4;
typedef __attribute__((address_space(1))) void void_g;
typedef __attribute__((address_space(3))) void void_l;

// fold 1/sqrt(128) * log2(e) into Q so scores come out in log2 domain
#define QSCALE (1.4426950408889634f * 0.08838834764831845f)

__device__ __forceinline__ short f2bf(float f) {
  union { float f; unsigned u; } v; v.f = f;
  return (short)((v.u + 0x7FFFu + ((v.u >> 16) & 1u)) >> 16);
}

__device__ __forceinline__ short8 pack8(const float4 a, const float4 b) {
  short8 r;
  r[0] = f2bf(a.x); r[1] = f2bf(a.y); r[2] = f2bf(a.z); r[3] = f2bf(a.w);
  r[4] = f2bf(b.x); r[5] = f2bf(b.y); r[6] = f2bf(b.z); r[7] = f2bf(b.w);
  return r;
}

__device__ __forceinline__ void gload16(char* l, const char* g) {
  __builtin_amdgcn_global_load_lds((void_g*)g, (void_l*)l, 16, 0, 0);
}

// ---------------------------------------------------------------------------
// Kernel 1: QKV projection.
//  Qb: [N][128] bf16 row-major, pre-scaled by QSCALE
//  Kb: 128 tiles of 32KB; elem (jr,e) at byte (jr*256+e*2)^((jr&7)<<4)
//  Vt: 128 tiles of 32KB; elem (d,jr)  at byte (d*256+jr*2)^((d&7)<<4)  (transposed)
// ---------------------------------------------------------------------------
__device__ __forceinline__ void mm16(const short8 (&af)[4], const float* __restrict__ W,
                                     const float* __restrict__ b, int l15, int lg,
                                     f32x4 (&acc)[8], float (&bias)[8]) {
#pragma unroll
  for (int nf = 0; nf < 8; ++nf) {
    acc[nf][0] = 0.f; acc[nf][1] = 0.f; acc[nf][2] = 0.f; acc[nf][3] = 0.f;
  }
#pragma unroll
  for (int kf = 0; kf < 4; ++kf) {
#pragma unroll
    for (int nf = 0; nf < 8; ++nf) {
      const float* wp = W + (size_t)(nf * 16 + l15) * DIM + kf * 32 + lg * 8;
      short8 bfr = pack8(*(const float4*)wp, *(const float4*)(wp + 4));
      acc[nf] = __builtin_amdgcn_mfma_f32_16x16x32_bf16(af[kf], bfr, acc[nf], 0, 0, 0);
    }
  }
#pragma unroll
  for (int nf = 0; nf < 8; ++nf) bias[nf] = b[nf * 16 + l15];
}

__global__ __launch_bounds__(256) void proj_kernel(
    const float* __restrict__ X,
    const float* __restrict__ Wq, const float* __restrict__ bq,
    const float* __restrict__ Wk, const float* __restrict__ bk,
    const float* __restrict__ Wv, const float* __restrict__ bv,
    short* __restrict__ Qb, char* __restrict__ Kb, char* __restrict__ Vt) {
  __shared__ short vtile[64][136];  // padded: rows r,r+4 land in different banks

  const int tid = threadIdx.x;
  const int w = tid >> 6, lane = tid & 63;
  const int l15 = lane & 15, lg = lane >> 4;
  const int i0 = blockIdx.x * 64;

  // A fragments from X (16 rows per wave)
  short8 af[4];
  {
    const int xrow = i0 + w * 16 + l15;
#pragma unroll
    for (int kf = 0; kf < 4; ++kf) {
      const float* xp = X + (size_t)xrow * DIM + kf * 32 + lg * 8;
      af[kf] = pack8(*(const float4*)xp, *(const float4*)(xp + 4));
    }
  }

  f32x4 acc[8];
  float bias[8];

  // ---- Q ----
  mm16(af, Wq, bq, l15, lg, acc, bias);
#pragma unroll
  for (int nf = 0; nf < 8; ++nf) {
    const int d = nf * 16 + l15;
#pragma unroll
    for (int rr = 0; rr < 4; ++rr) {
      const int i = i0 + w * 16 + lg * 4 + rr;
      Qb[(size_t)i * DIM + d] = f2bf((acc[nf][rr] + bias[nf]) * QSCALE);
    }
  }
  // ---- K ----
  mm16(af, Wk, bk, l15, lg, acc, bias);
#pragma unroll
  for (int nf = 0; nf < 8; ++nf) {
    const int d = nf * 16 + l15;
#pragma unroll
    for (int rr = 0; rr < 4; ++rr) {
      const int i = i0 + w * 16 + lg * 4 + rr;
      const int jt = i >> 7, jr = i & 127;
      const int off = (jr * 256 + d * 2) ^ ((jr & 7) << 4);
      *(short*)(Kb + (size_t)jt * 32768 + off) = f2bf(acc[nf][rr] + bias[nf]);
    }
  }
  // ---- V ---- (to LDS, then transposed global write)
  mm16(af, Wv, bv, l15, lg, acc, bias);
#pragma unroll
  for (int nf = 0; nf < 8; ++nf) {
    const int d = nf * 16 + l15;
#pragma unroll
    for (int rr = 0; rr < 4; ++rr) {
      vtile[w * 16 + lg * 4 + rr][d] = f2bf(acc[nf][rr] + bias[nf]);
    }
  }
  __syncthreads();
#pragma unroll
  for (int it = 0; it < 4; ++it) {
    const int task = tid + it * 256;   // 0..1023
    const int d = task >> 3, c = task & 7;
    short8 st;
#pragma unroll
    for (int s2 = 0; s2 < 8; ++s2) st[s2] = vtile[c * 8 + s2][d];
    const int gj = i0 + c * 8;
    const int jt = gj >> 7, jr = gj & 127;
    const int off = (d * 256 + jr * 2) ^ ((d & 7) << 4);
    *(short8*)(Vt + (size_t)jt * 32768 + off) = st;
  }
}

// ---------------------------------------------------------------------------
// Kernel 2: fused masked-softmax attention.
// 256 blocks x 256 threads (4 waves). Block owns 64 i-rows.
// wave (wr,wc): S/out quadrant rows [wr*32,+32) x cols [wc*64,+64).
// ---------------------------------------------------------------------------
__device__ __forceinline__ void stage_tile(const char* KbG, const char* VtG, int tt,
                                           char* kdst, char* vdst, int tid) {
  const char* gk = KbG + (size_t)tt * 32768;
  const char* gv = VtG + (size_t)tt * 32768;
  const int o = tid * 16;
#pragma unroll
  for (int u = 0; u < 8; ++u) {
    gload16(kdst + u * 4096 + o, gk + u * 4096 + o);
    gload16(vdst + u * 4096 + o, gv + u * 4096 + o);
  }
}

__device__ __forceinline__ void load_adj_tile(int (&dst)[2][4][4], const int* __restrict__ adj,
                                              int tt, int i0, int wr, int wc, int l15, int lg) {
#pragma unroll
  for (int mf = 0; mf < 2; ++mf) {
#pragma unroll
    for (int rr = 0; rr < 4; ++rr) {
      const size_t row = (size_t)(i0 + wr * 32 + mf * 16 + lg * 4 + rr);
      const int* ap = adj + row * NTOK + tt * 128 + wc * 64 + l15;
#pragma unroll
      for (int nf = 0; nf < 4; ++nf) dst[mf][rr][nf] = ap[nf * 16];
    }
  }
}

__device__ __forceinline__ void attn_step(
    int t, const char* KbG, const char* VtG, const int* __restrict__ adj,
    const char* klsC, const char* vlsC, char* klsN, char* vlsN, char* pls,
    const short8 (&qf)[2][4], f32x4 (&acc)[2][4], float (&dsum)[8],
    int (&adjC)[2][4][4], int (&adjN)[2][4][4],
    int i0, int wr, int wc, int l15, int lg, int tid) {
  const int tn = (t + 1) & (NJT - 1);  // wraps harmlessly on last step

  // prefetch next K/V tile into the other LDS buffer + next adj tile into regs
  stage_tile(KbG, VtG, tn, klsN, vlsN, tid);
  load_adj_tile(adjN, adj, tn, i0, wr, wc, l15, lg);

  // ---- S = Q @ K^T (log2-scaled already) ----
  f32x4 s[2][4];
#pragma unroll
  for (int mf = 0; mf < 2; ++mf) {
#pragma unroll
    for (int nf = 0; nf < 4; ++nf) {
      s[mf][nf][0] = 0.f; s[mf][nf][1] = 0.f; s[mf][nf][2] = 0.f; s[mf][nf][3] = 0.f;
    }
  }
#pragma unroll
  for (int kf = 0; kf < 4; ++kf) {
#pragma unroll
    for (int nf = 0; nf < 4; ++nf) {
      const int j = wc * 64 + nf * 16 + l15;
      const int e0 = kf * 32 + lg * 8;
      const int off = (j * 256 + e0 * 2) ^ ((j & 7) << 4);
      short8 bfr = *(const short8*)(klsC + off);
#pragma unroll
      for (int mf = 0; mf < 2; ++mf)
        s[mf][nf] = __builtin_amdgcn_mfma_f32_16x16x32_bf16(qf[mf][kf], bfr, s[mf][nf], 0, 0, 0);
    }
  }

  // ---- P = exp2(adj ? s : 0); row-sum; write P to LDS (swizzled) ----
#pragma unroll
  for (int mf = 0; mf < 2; ++mf) {
#pragma unroll
    for (int nf = 0; nf < 4; ++nf) {
#pragma unroll
      for (int rr = 0; rr < 4; ++rr) {
        const float sv = adjC[mf][rr][nf] ? s[mf][nf][rr] : 0.0f;
        const float p = __builtin_exp2f(sv);
        dsum[mf * 4 + rr] += p;
        const int irow = wr * 32 + mf * 16 + lg * 4 + rr;
        const int jcol = wc * 64 + nf * 16 + l15;
        const int off = (irow * 256 + jcol * 2) ^ ((irow & 7) << 4);
        *(short*)(pls + off) = f2bf(p);
      }
    }
  }
  __syncthreads();  // P visible to all waves (also drains staged loads)

  // ---- acc += P @ V ----
#pragma unroll
  for (int kf = 0; kf < 4; ++kf) {
    short8 pa[2];
#pragma unroll
    for (int mf = 0; mf < 2; ++mf) {
      const int irow = wr * 32 + mf * 16 + l15;
      const int j0 = kf * 32 + lg * 8;
      const int off = (irow * 256 + j0 * 2) ^ ((irow & 7) << 4);
      pa[mf] = *(const short8*)(pls + off);
    }
#pragma unroll
    for (int nf = 0; nf < 4; ++nf) {
      const int d = wc * 64 + nf * 16 + l15;
      const int j0 = kf * 32 + lg * 8;
      const int off = (d * 256 + j0 * 2) ^ ((d & 7) << 4);
      short8 vf = *(const short8*)(vlsC + off);
#pragma unroll
      for (int mf = 0; mf < 2; ++mf)
        acc[mf][nf] = __builtin_amdgcn_mfma_f32_16x16x32_bf16(pa[mf], vf, acc[mf][nf], 0, 0, 0);
    }
  }
  __syncthreads();  // WAR: P rewritten next step; next buffers ready
}

__global__ __launch_bounds__(256, 1) void attn_kernel(
    const short* __restrict__ QbG, const char* __restrict__ KbG,
    const char* __restrict__ VtG, const int* __restrict__ adj,
    float* __restrict__ out) {
  __shared__ __align__(16) char kls[2][32768];
  __shared__ __align__(16) char vls[2][32768];
  __shared__ __align__(16) char pls[16384];
  __shared__ float denp[2][64];

  const int tid = threadIdx.x;
  const int w = tid >> 6, lane = tid & 63;
  const int l15 = lane & 15, lg = lane >> 4;
  const int wr = w >> 1, wc = w & 1;
  const int i0 = blockIdx.x * 64;

  // Q fragments (persist in registers)
  short8 qf[2][4];
#pragma unroll
  for (int mf = 0; mf < 2; ++mf) {
    const int i = i0 + wr * 32 + mf * 16 + l15;
#pragma unroll
    for (int kf = 0; kf < 4; ++kf)
      qf[mf][kf] = *(const short8*)(QbG + (size_t)i * DIM + kf * 32 + lg * 8);
  }

  f32x4 acc[2][4];
#pragma unroll
  for (int mf = 0; mf < 2; ++mf)
#pragma unroll
    for (int nf = 0; nf < 4; ++nf) {
      acc[mf][nf][0] = 0.f; acc[mf][nf][1] = 0.f; acc[mf][nf][2] = 0.f; acc[mf][nf][3] = 0.f;
    }
  float dsum[8] = {0.f, 0.f, 0.f, 0.f, 0.f, 0.f, 0.f, 0.f};
  int adjA[2][4][4], adjB[2][4][4];

  // prologue: tile 0
  stage_tile(KbG, VtG, 0, kls[0], vls[0], tid);
  load_adj_tile(adjA, adj, 0, i0, wr, wc, l15, lg);
  __syncthreads();  // drains vmcnt -> tile 0 + adjA ready

  for (int t = 0; t < NJT; t += 2) {
    attn_step(t,     KbG, VtG, adj, kls[0], vls[0], kls[1], vls[1], pls,
              qf, acc, dsum, adjA, adjB, i0, wr, wc, l15, lg, tid);
    attn_step(t + 1, KbG, VtG, adj, kls[1], vls[1], kls[0], vls[0], pls,
              qf, acc, dsum, adjB, adjA, i0, wr, wc, l15, lg, tid);
  }

  // deterministic denominator reduction: sum over the 16 lanes of each l15-group
#pragma unroll
  for (int q = 0; q < 8; ++q) {
    float v = dsum[q];
    v += __shfl_xor(v, 1);
    v += __shfl_xor(v, 2);
    v += __shfl_xor(v, 4);
    v += __shfl_xor(v, 8);
    if (l15 == 0) {
      const int mf = q >> 2, rr = q & 3;
      denp[wc][wr * 32 + mf * 16 + lg * 4 + rr] = v;
    }
  }
  __syncthreads();

#pragma unroll
  for (int mf = 0; mf < 2; ++mf) {
#pragma unroll
    for (int nf = 0; nf < 4; ++nf) {
#pragma unroll
      for (int rr = 0; rr < 4; ++rr) {
        const int il = wr * 32 + mf * 16 + lg * 4 + rr;
        const float den = denp[0][il] + denp[1][il];
        out[(size_t)(i0 + il) * DIM + wc * 64 + nf * 16 + l15] = acc[mf][nf][rr] / den;
      }
    }
  }
}

// ---------------------------------------------------------------------------
extern "C" void kernel_launch(void* const* d_in, const int* in_sizes, int n_in,
                              void* d_out, int out_size, void* d_ws, size_t ws_size,
                              hipStream_t stream) {
  const float* X  = (const float*)d_in[0];
  const float* Wq = (const float*)d_in[1];
  const float* bq = (const float*)d_in[2];
  const float* Wk = (const float*)d_in[3];
  const float* bk = (const float*)d_in[4];
  const float* Wv = (const float*)d_in[5];
  const float* bv = (const float*)d_in[6];
  const int*  adj = (const int*)d_in[7];
  float* out = (float*)d_out;

  char* ws = (char*)d_ws;
  short* Qb = (short*)ws;                       // 4 MB bf16 [N][128]
  char*  Kb = ws + ((size_t)4 << 20);           // 4 MB swizzled tiles
  char*  Vt = ws + ((size_t)8 << 20);           // 4 MB swizzled transposed tiles

  proj_kernel<<<256, 256, 0, stream>>>(X, Wq, bq, Wk, bk, Wv, bv, Qb, Kb, Vt);
  attn_kernel<<<256, 256, 0, stream>>>(Qb, Kb, Vt, adj, out);
}

// Round 2
// 450.422 us; speedup vs baseline: 1.0058x; 1.0058x over previous
//
#include <hip/hip_runtime.h>

#define NTOK 16384
#define DIM  128
#define NJT  128   // number of 128-wide j tiles
#define RB   32    // i-rows per attn block

typedef __attribute__((ext_vector_type(8))) short short8;
typedef __attribute__((ext_vector_type(4))) float f32x4;

// fold 1/sqrt(128) * log2(e) into Q so scores come out in log2 domain
#define QSCALE (1.4426950408889634f * 0.08838834764831845f)

// barrier that drains LDS ops only -- global loads stay in flight
#define BAR() asm volatile("s_waitcnt lgkmcnt(0)\n\ts_barrier" ::: "memory")

__device__ __forceinline__ short f2bf(float f) {
  union { float f; unsigned u; } v; v.f = f;
  return (short)((v.u + 0x7FFFu + ((v.u >> 16) & 1u)) >> 16);
}

__device__ __forceinline__ short8 pack8(const float4 a, const float4 b) {
  short8 r;
  r[0] = f2bf(a.x); r[1] = f2bf(a.y); r[2] = f2bf(a.z); r[3] = f2bf(a.w);
  r[4] = f2bf(b.x); r[5] = f2bf(b.y); r[6] = f2bf(b.z); r[7] = f2bf(b.w);
  return r;
}

// fragment-contiguous chunk offset: chunk (t, kf, lg, r) is 16 bytes
__device__ __forceinline__ int kvoff(int t, int kf, int lg, int r) {
  return ((((t * 4 + kf) * 4 + lg) * 128) + r) * 16;
}

// pls swizzle: 2-way (free) on both b16 writes and b128 reads
__device__ __forceinline__ int psw(int r) { return ((r >> 1) & 7) << 4; }

// ---------------------------------------------------------------------------
// Kernel 1: QKV projection.
//  Qb: [N][128] bf16 row-major, pre-scaled by QSCALE
//  K2: fragment-contiguous chunks; chunk(t,kf,lg,j) = K[t*128+j][kf*32+lg*8 .. +8]
//  V2: fragment-contiguous chunks; chunk(t,kf,lg,d) = V[t*128+kf*32+lg*8 .. +8][d]
// ---------------------------------------------------------------------------
__device__ __forceinline__ void mm16(const short8 (&af)[4], const float* __restrict__ W,
                                     const float* __restrict__ b, int l15, int lg,
                                     f32x4 (&acc)[8], float (&bias)[8]) {
#pragma unroll
  for (int nf = 0; nf < 8; ++nf) {
    acc[nf][0] = 0.f; acc[nf][1] = 0.f; acc[nf][2] = 0.f; acc[nf][3] = 0.f;
  }
#pragma unroll
  for (int kf = 0; kf < 4; ++kf) {
#pragma unroll
    for (int nf = 0; nf < 8; ++nf) {
      const float* wp = W + (size_t)(nf * 16 + l15) * DIM + kf * 32 + lg * 8;
      short8 bfr = pack8(*(const float4*)wp, *(const float4*)(wp + 4));
      acc[nf] = __builtin_amdgcn_mfma_f32_16x16x32_bf16(af[kf], bfr, acc[nf], 0, 0, 0);
    }
  }
#pragma unroll
  for (int nf = 0; nf < 8; ++nf) bias[nf] = b[nf * 16 + l15];
}

__global__ __launch_bounds__(256) void proj_kernel(
    const float* __restrict__ X,
    const float* __restrict__ Wq, const float* __restrict__ bq,
    const float* __restrict__ Wk, const float* __restrict__ bk,
    const float* __restrict__ Wv, const float* __restrict__ bv,
    short* __restrict__ Qb, char* __restrict__ K2, char* __restrict__ V2) {
  __shared__ short ktile[64][136];
  __shared__ short vtile[64][136];

  const int tid = threadIdx.x;
  const int w = tid >> 6, lane = tid & 63;
  const int l15 = lane & 15, lg = lane >> 4;
  const int i0 = blockIdx.x * 64;
  const int t = i0 >> 7, jl0 = i0 & 127;

  // A fragments from X (16 rows per wave)
  short8 af[4];
  {
    const int xrow = i0 + w * 16 + l15;
#pragma unroll
    for (int kf = 0; kf < 4; ++kf) {
      const float* xp = X + (size_t)xrow * DIM + kf * 32 + lg * 8;
      af[kf] = pack8(*(const float4*)xp, *(const float4*)(xp + 4));
    }
  }

  f32x4 acc[8];
  float bias[8];

  // ---- Q ----
  mm16(af, Wq, bq, l15, lg, acc, bias);
#pragma unroll
  for (int nf = 0; nf < 8; ++nf) {
    const int d = nf * 16 + l15;
#pragma unroll
    for (int rr = 0; rr < 4; ++rr) {
      const int i = i0 + w * 16 + lg * 4 + rr;
      Qb[(size_t)i * DIM + d] = f2bf((acc[nf][rr] + bias[nf]) * QSCALE);
    }
  }

  // ---- K ---- (to LDS row-major, then coalesced fragment-chunk writes)
  mm16(af, Wk, bk, l15, lg, acc, bias);
#pragma unroll
  for (int nf = 0; nf < 8; ++nf) {
    const int d = nf * 16 + l15;
#pragma unroll
    for (int rr = 0; rr < 4; ++rr)
      ktile[w * 16 + lg * 4 + rr][d] = f2bf(acc[nf][rr] + bias[nf]);
  }

  // ---- V ---- (to LDS row-major, then transposed fragment-chunk writes)
  mm16(af, Wv, bv, l15, lg, acc, bias);
#pragma unroll
  for (int nf = 0; nf < 8; ++nf) {
    const int d = nf * 16 + l15;
#pragma unroll
    for (int rr = 0; rr < 4; ++rr)
      vtile[w * 16 + lg * 4 + rr][d] = f2bf(acc[nf][rr] + bias[nf]);
  }
  __syncthreads();

  // K chunks: task = octet o (16) x local row (64)
#pragma unroll
  for (int it = 0; it < 4; ++it) {
    const int task = it * 256 + tid;
    const int o = task >> 6, jr = task & 63;
    const int kf = o >> 2, lg2 = o & 3;
    short8 st = *(const short8*)&ktile[jr][o * 8];
    *(short8*)(K2 + kvoff(t, kf, lg2, jl0 + jr)) = st;
  }

  // V chunks: task = c (8 j-octets) x d (128)
#pragma unroll
  for (int it = 0; it < 4; ++it) {
    const int task = it * 256 + tid;
    const int c = task >> 7, d = task & 127;
    short8 st;
#pragma unroll
    for (int s2 = 0; s2 < 8; ++s2) st[s2] = vtile[c * 8 + s2][d];
    const int jl = jl0 + c * 8;
    const int kf = jl >> 5, lg2 = (jl >> 3) & 3;
    *(short8*)(V2 + kvoff(t, kf, lg2, d)) = st;
  }
}

// ---------------------------------------------------------------------------
// Kernel 2: fused masked-softmax attention.
// 512 blocks x 256 threads (4 waves). Block owns 32 i-rows; wave wc owns
// the 32-wide j-slice (for QK/P) and d-slice (for PV/out) [wc*32, +32).
// K/V read directly from L2 (fragment-contiguous); LDS only for P exchange.
// ---------------------------------------------------------------------------
__device__ __forceinline__ void load_adj(int (&dst)[2][4][2], const int* __restrict__ adj,
                                         int tt, int i0, int wc, int l15, int lg) {
#pragma unroll
  for (int mf = 0; mf < 2; ++mf) {
#pragma unroll
    for (int rr = 0; rr < 4; ++rr) {
      const size_t row = (size_t)(i0 + mf * 16 + lg * 4 + rr);
      const int* ap = adj + row * NTOK + tt * 128 + wc * 32 + l15;
      dst[mf][rr][0] = ap[0];
      dst[mf][rr][1] = ap[16];
    }
  }
}

__device__ __forceinline__ void attn_step(
    int t, const char* __restrict__ K2, const char* __restrict__ V2,
    const int* __restrict__ adj, char* pls,
    const short8 (&qf)[2][4], f32x4 (&acc)[2][2], float (&dsum)[8],
    int (&adjC)[2][4][2], int (&adjN)[2][4][2],
    int i0, int wc, int l15, int lg) {
  // ---- S = Q @ K^T (log2-scaled already) ----
  f32x4 s[2][2];
#pragma unroll
  for (int mf = 0; mf < 2; ++mf)
#pragma unroll
    for (int nf = 0; nf < 2; ++nf) {
      s[mf][nf][0] = 0.f; s[mf][nf][1] = 0.f; s[mf][nf][2] = 0.f; s[mf][nf][3] = 0.f;
    }
#pragma unroll
  for (int kf = 0; kf < 4; ++kf) {
#pragma unroll
    for (int nf = 0; nf < 2; ++nf) {
      const int jl = wc * 32 + nf * 16 + l15;
      short8 bfr = *(const short8*)(K2 + kvoff(t, kf, lg, jl));
#pragma unroll
      for (int mf = 0; mf < 2; ++mf)
        s[mf][nf] = __builtin_amdgcn_mfma_f32_16x16x32_bf16(qf[mf][kf], bfr, s[mf][nf], 0, 0, 0);
    }
  }

  // prefetch next adj tile into the other register buffer
  load_adj(adjN, adj, (t + 1) & (NJT - 1), i0, wc, l15, lg);

  // prefetch V fragments for this tile (independent of P)
  short8 vf[4][2];
#pragma unroll
  for (int kf = 0; kf < 4; ++kf)
#pragma unroll
    for (int nf = 0; nf < 2; ++nf) {
      const int d = wc * 32 + nf * 16 + l15;
      vf[kf][nf] = *(const short8*)(V2 + kvoff(t, kf, lg, d));
    }

  // ---- P = exp2(adj ? s : 0); row-sum; write P to LDS (swizzled) ----
#pragma unroll
  for (int mf = 0; mf < 2; ++mf)
#pragma unroll
    for (int nf = 0; nf < 2; ++nf)
#pragma unroll
      for (int rr = 0; rr < 4; ++rr) {
        const float sv = adjC[mf][rr][nf] ? s[mf][nf][rr] : 0.0f;
        const float p = __builtin_exp2f(sv);
        dsum[mf * 4 + rr] += p;
        const int r = mf * 16 + lg * 4 + rr;
        const int c = wc * 32 + nf * 16 + l15;
        *(short*)(pls + ((r * 256 + c * 2) ^ psw(r))) = f2bf(p);
      }
  BAR();  // P visible to all waves (LDS drain only; global loads stay in flight)

  // ---- acc += P @ V ----
#pragma unroll
  for (int kf = 0; kf < 4; ++kf) {
    short8 pa[2];
#pragma unroll
    for (int mf = 0; mf < 2; ++mf) {
      const int row = mf * 16 + l15;
      pa[mf] = *(const short8*)(pls + ((row * 256 + (kf * 32 + lg * 8) * 2) ^ psw(row)));
    }
#pragma unroll
    for (int nf = 0; nf < 2; ++nf)
#pragma unroll
      for (int mf = 0; mf < 2; ++mf)
        acc[mf][nf] = __builtin_amdgcn_mfma_f32_16x16x32_bf16(pa[mf], vf[kf][nf], acc[mf][nf], 0, 0, 0);
  }
  BAR();  // WAR: pls rewritten next step
}

__global__ __launch_bounds__(256, 2) void attn_kernel(
    const short* __restrict__ QbG, const char* __restrict__ K2,
    const char* __restrict__ V2, const int* __restrict__ adj,
    float* __restrict__ out) {
  __shared__ __align__(16) char pls[RB * 256];   // 8 KB
  __shared__ float denp[4][RB];

  const int tid = threadIdx.x;
  const int wc = tid >> 6, lane = tid & 63;
  const int l15 = lane & 15, lg = lane >> 4;
  const int i0 = blockIdx.x * RB;

  // Q fragments (all 32 block rows, persist in registers)
  short8 qf[2][4];
#pragma unroll
  for (int mf = 0; mf < 2; ++mf) {
    const int i = i0 + mf * 16 + l15;
#pragma unroll
    for (int kf = 0; kf < 4; ++kf)
      qf[mf][kf] = *(const short8*)(QbG + (size_t)i * DIM + kf * 32 + lg * 8);
  }

  f32x4 acc[2][2];
#pragma unroll
  for (int mf = 0; mf < 2; ++mf)
#pragma unroll
    for (int nf = 0; nf < 2; ++nf) {
      acc[mf][nf][0] = 0.f; acc[mf][nf][1] = 0.f; acc[mf][nf][2] = 0.f; acc[mf][nf][3] = 0.f;
    }
  float dsum[8] = {0.f, 0.f, 0.f, 0.f, 0.f, 0.f, 0.f, 0.f};
  int adjA[2][4][2], adjB[2][4][2];

  load_adj(adjA, adj, 0, i0, wc, l15, lg);

  for (int t = 0; t < NJT; t += 2) {
    attn_step(t,     K2, V2, adj, pls, qf, acc, dsum, adjA, adjB, i0, wc, l15, lg);
    attn_step(t + 1, K2, V2, adj, pls, qf, acc, dsum, adjB, adjA, i0, wc, l15, lg);
  }

  // deterministic denominator reduction over the 16 lanes of each l15-group
#pragma unroll
  for (int q = 0; q < 8; ++q) {
    float v = dsum[q];
    v += __shfl_xor(v, 1);
    v += __shfl_xor(v, 2);
    v += __shfl_xor(v, 4);
    v += __shfl_xor(v, 8);
    if (l15 == 0) {
      const int mf = q >> 2, rr = q & 3;
      denp[wc][mf * 16 + lg * 4 + rr] = v;
    }
  }
  __syncthreads();

#pragma unroll
  for (int mf = 0; mf < 2; ++mf)
#pragma unroll
    for (int nf = 0; nf < 2; ++nf)
#pragma unroll
      for (int rr = 0; rr < 4; ++rr) {
        const int r = mf * 16 + lg * 4 + rr;
        const float den = denp[0][r] + denp[1][r] + denp[2][r] + denp[3][r];
        out[(size_t)(i0 + r) * DIM + wc * 32 + nf * 16 + l15] = acc[mf][nf][rr] / den;
      }
}

// ---------------------------------------------------------------------------
extern "C" void kernel_launch(void* const* d_in, const int* in_sizes, int n_in,
                              void* d_out, int out_size, void* d_ws, size_t ws_size,
                              hipStream_t stream) {
  const float* X  = (const float*)d_in[0];
  const float* Wq = (const float*)d_in[1];
  const float* bq = (const float*)d_in[2];
  const float* Wk = (const float*)d_in[3];
  const float* bk = (const float*)d_in[4];
  const float* Wv = (const float*)d_in[5];
  const float* bv = (const float*)d_in[6];
  const int*  adj = (const int*)d_in[7];
  float* out = (float*)d_out;

  char* ws = (char*)d_ws;
  short* Qb = (short*)ws;                       // 4 MB bf16 [N][128]
  char*  K2 = ws + ((size_t)4 << 20);           // 4 MB fragment-contiguous K
  char*  V2 = ws + ((size_t)8 << 20);           // 4 MB fragment-contiguous V^T

  proj_kernel<<<256, 256, 0, stream>>>(X, Wq, bq, Wk, bk, Wv, bv, Qb, K2, V2);
  attn_kernel<<<NTOK / RB, 256, 0, stream>>>(Qb, K2, V2, adj, out);
}